// Round 6
// baseline (420.411 us; speedup 1.0000x reference)
//
#include <hip/hip_runtime.h>

// Problem constants (fixed by the reference)
#define NHEADS 8
#define NKVH   2
#define HD     256
#define SEQ    4096
#define HID    2048
#define QKVN   3072   // (NH + 2*NKV) * D
#define SCAL   (1.0f/256.0f)

typedef __attribute__((ext_vector_type(8))) __bf16 bf16x8;
typedef __attribute__((ext_vector_type(4))) float  f32x4;
typedef __attribute__((ext_vector_type(4))) unsigned int u32x4;

__device__ __forceinline__ unsigned short f2bf(float f) {
  unsigned int u = __builtin_bit_cast(unsigned int, f);
  u += 0x7fffu + ((u >> 16) & 1u);          // round-to-nearest-even
  return (unsigned short)(u >> 16);
}
__device__ __forceinline__ float bf2f(unsigned short b) {
  return __builtin_bit_cast(float, (unsigned int)b << 16);
}
// packed f32 pair -> bf16 pair (low = a, high = b)
__device__ __forceinline__ unsigned int cvtpk(float a, float b) {
  unsigned int r;
  asm("v_cvt_pk_bf16_f32 %0, %1, %2" : "=v"(r) : "v"(a), "v"(b));
  return r;
}

// async global->LDS, 16B per lane (linear LDS dest = wave base + lane*16)
__device__ __forceinline__ void async_copy16(const void* g, void* l) {
  __builtin_amdgcn_global_load_lds(
      (__attribute__((address_space(1))) void*)(g),
      (__attribute__((address_space(3))) void*)(l), 16, 0, 0);
}

// ---------------------------------------------------------------- fp32->bf16
__global__ __launch_bounds__(256) void cvt_bf16(const float* __restrict__ in,
                                                unsigned short* __restrict__ out,
                                                int n4) {
  int i = blockIdx.x * 256 + threadIdx.x;
  if (i >= n4) return;
  float4 v = reinterpret_cast<const float4*>(in)[i];
  ushort4 o;
  o.x = f2bf(v.x); o.y = f2bf(v.y); o.z = f2bf(v.z); o.w = f2bf(v.w);
  reinterpret_cast<ushort4*>(out)[i] = o;
}

// ------------------------------------------------------- C = A(M,K) * B(N,K)^T
// 128x128 tile, BK=64, 4 waves as 2x2 of 64x64.  (verified rounds 1-5)
template <bool OUT_BF16>
__global__ __launch_bounds__(256) void gemm_bt(const unsigned short* __restrict__ A,
                                               const unsigned short* __restrict__ B,
                                               void* __restrict__ C,
                                               int M, int N, int K) {
  __shared__ __align__(16) unsigned short Als[128 * 64];
  __shared__ __align__(16) unsigned short Bls[128 * 64];
  const int t    = threadIdx.x;
  const int lane = t & 63;
  const int wid  = t >> 6;
  const int wr = wid >> 1, wc = wid & 1;
  const int l15 = lane & 15, lg = lane >> 4;
  const int m0 = blockIdx.y * 128, n0 = blockIdx.x * 128;

  f32x4 acc[4][4] = {};

  for (int k0 = 0; k0 < K; k0 += 64) {
    __syncthreads();                                  // LDS reuse fence
#pragma unroll
    for (int i = 0; i < 4; ++i) {
      int c   = i * 256 + t;                          // 16B chunk index 0..1023
      int kc  = c >> 9;
      int row = (c >> 2) & 127;
      int j8  = (c & 3) ^ (row & 3);                  // inverse-swizzled source
      int gcol = k0 + kc * 32 + j8 * 8;
      async_copy16(A + (size_t)(m0 + row) * K + gcol, Als + c * 8);
      async_copy16(B + (size_t)(n0 + row) * K + gcol, Bls + c * 8);
    }
    __syncthreads();                                  // drains vmcnt before use
#pragma unroll
    for (int kc = 0; kc < 2; ++kc) {
      bf16x8 af[4], bfr[4];
#pragma unroll
      for (int m = 0; m < 4; ++m) {
        int row   = wr * 64 + m * 16 + l15;
        int chunk = kc * 512 + row * 4 + (lg ^ (row & 3));
        af[m] = *reinterpret_cast<const bf16x8*>(Als + chunk * 8);
      }
#pragma unroll
      for (int n = 0; n < 4; ++n) {
        int row   = wc * 64 + n * 16 + l15;
        int chunk = kc * 512 + row * 4 + (lg ^ (row & 3));
        bfr[n] = *reinterpret_cast<const bf16x8*>(Bls + chunk * 8);
      }
#pragma unroll
      for (int m = 0; m < 4; ++m)
#pragma unroll
        for (int n = 0; n < 4; ++n)
          acc[m][n] = __builtin_amdgcn_mfma_f32_16x16x32_bf16(af[m], bfr[n],
                                                              acc[m][n], 0, 0, 0);
    }
  }

#pragma unroll
  for (int m = 0; m < 4; ++m) {
#pragma unroll
    for (int n = 0; n < 4; ++n) {
      int col = n0 + wc * 64 + n * 16 + l15;
#pragma unroll
      for (int r = 0; r < 4; ++r) {
        int rowg = m0 + wr * 64 + m * 16 + lg * 4 + r;   // C/D: row=(l>>4)*4+r
        if constexpr (OUT_BF16)
          reinterpret_cast<unsigned short*>(C)[(size_t)rowg * N + col] =
              f2bf(acc[m][n][r]);
        else
          reinterpret_cast<float*>(C)[(size_t)rowg * N + col] = acc[m][n][r];
      }
    }
  }
}

// --------------------------------------------- RMSNorm + RoPE + layout split
__global__ __launch_bounds__(256) void postproc(const unsigned short* __restrict__ qkv,
                                                const float* __restrict__ cosb,
                                                const float* __restrict__ sinb,
                                                unsigned short* __restrict__ q,
                                                unsigned short* __restrict__ k,
                                                unsigned short* __restrict__ vt) {
  const int wid = threadIdx.x >> 6, lane = threadIdx.x & 63;
  const int task = blockIdx.x * 4 + wid;          // 0 .. SEQ*12-1
  const int s = task / 12, comp = task % 12;

  ushort4 raw = reinterpret_cast<const ushort4*>(qkv + (size_t)task * 256)[lane];
  float x0 = bf2f(raw.x), x1 = bf2f(raw.y), x2 = bf2f(raw.z), x3 = bf2f(raw.w);

  float ss = x0 * x0 + x1 * x1 + x2 * x2 + x3 * x3;
#pragma unroll
  for (int m = 1; m < 64; m <<= 1) ss += __shfl_xor(ss, m);
  float inv = rsqrtf(ss * (1.0f / 256.0f) + 1e-6f);
  x0 *= inv; x1 *= inv; x2 *= inv; x3 *= inv;

  if (comp < 10) {  // RoPE: lane d-range 4*lane..4*lane+3, partner ±128
    float4 c  = reinterpret_cast<const float4*>(cosb + (size_t)s * 256)[lane];
    float4 sn = reinterpret_cast<const float4*>(sinb + (size_t)s * 256)[lane];
    float p0 = __shfl_xor(x0, 32), p1 = __shfl_xor(x1, 32);
    float p2 = __shfl_xor(x2, 32), p3 = __shfl_xor(x3, 32);
    float sg = (lane < 32) ? -1.0f : 1.0f;       // rotate_half sign
    x0 = x0 * c.x + sg * p0 * sn.x;
    x1 = x1 * c.y + sg * p1 * sn.y;
    x2 = x2 * c.z + sg * p2 * sn.z;
    x3 = x3 * c.w + sg * p3 * sn.w;
  }

  if (comp < 8) {
    ushort4 o;
    o.x = f2bf(x0 * SCAL); o.y = f2bf(x1 * SCAL);
    o.z = f2bf(x2 * SCAL); o.w = f2bf(x3 * SCAL);
    reinterpret_cast<ushort4*>(q + ((size_t)s * NHEADS + comp) * 256)[lane] = o;
  } else if (comp < 10) {
    ushort4 o;
    o.x = f2bf(x0); o.y = f2bf(x1); o.z = f2bf(x2); o.w = f2bf(x3);
    reinterpret_cast<ushort4*>(k + ((size_t)(comp - 8) * SEQ + s) * 256)[lane] = o;
  } else {  // v -> V^T[kvh][d][s]
    size_t base = (size_t)(comp - 10) * 256 * SEQ + s;
    int d0 = lane * 4;
    vt[base + (size_t)(d0 + 0) * SEQ] = f2bf(x0);
    vt[base + (size_t)(d0 + 1) * SEQ] = f2bf(x1);
    vt[base + (size_t)(d0 + 2) * SEQ] = f2bf(x2);
    vt[base + (size_t)(d0 + 3) * SEQ] = f2bf(x3);
  }
}

// --------------------------------------------------- causal flash attention
// v4: 4 waves x 32 q-rows (two 16-q groups) per block; each kf/vf LDS read
// feeds 2 MFMAs (halved LDS-read/FLOP).  K swizzled (2-way free); V padded to
// 40-elem rows (conflict-free, 2-way).  P redistribution fully in-register
// via v_cvt_pk_bf16_f32 + ds_bpermute (no P LDS, no cross-wave sync).
// LDS = 72 KB -> 2 blocks/CU.  Split-KV chunking identical to round 5.
__global__ __launch_bounds__(256, 2) void flash(const unsigned short* __restrict__ q,
                                                const unsigned short* __restrict__ k,
                                                const unsigned short* __restrict__ vt,
                                                unsigned short* __restrict__ attn,
                                                unsigned short* __restrict__ opart,
                                                float* __restrict__ ml) {
  extern __shared__ __align__(16) unsigned short lds[];
  unsigned short* Kls = lds;            // [2][32 rows * 256]   2 x 16 KB
  unsigned short* Vls = lds + 16384;    // [2][256 rows * 40]   2 x 20 KB

  const int tid  = threadIdx.x;
  const int lane = tid & 63, wid = tid >> 6;
  const int l15 = lane & 15, lg = lane >> 4;

  const int bid = blockIdx.x;
  const int h = bid & 7, kvh = h >> 2;
  const int idx = bid >> 3;
  const int b  = (idx < 32) ? idx : 63 - idx;
  const int c  = (idx < 32) ? 0 : 1;
  const int t0 = c ? (2 * b + 2) : 0;
  const int t1 = c ? (4 * b + 3) : (2 * b + 1);
  const int qb = b * 128 + wid * 32;             // this wave's 32 q-rows

  const unsigned short* kbase = k  + (size_t)kvh * SEQ * 256;
  const unsigned short* vtb   = vt + (size_t)kvh * 256 * SEQ;

  // Q fragments: group g rows qb+16g+l15, k-chunk lg
  bf16x8 qf[2][8];
#pragma unroll
  for (int g = 0; g < 2; ++g) {
    const unsigned short* qrow =
        q + ((size_t)(qb + 16 * g + l15) * NHEADS + h) * 256 + lg * 8;
#pragma unroll
    for (int kc = 0; kc < 8; ++kc)
      qf[g][kc] = *reinterpret_cast<const bf16x8*>(qrow + kc * 32);
  }

  f32x4 o[16][2];
#pragma unroll
  for (int i = 0; i < 16; ++i)
#pragma unroll
    for (int g = 0; g < 2; ++g) o[i][g] = f32x4{0.f, 0.f, 0.f, 0.f};
  float m0r = -1e30f, l0r = 0.f, m1r = -1e30f, l1r = 0.f;

  // stage K (XOR-swizzled) + V (pad-40 rows) for kv range [t*32, t*32+31]
  auto stage = [&](int bb, int t) {
    const int kvb = t * 32;
#pragma unroll
    for (int i = 0; i < 4; ++i) {                  // K: 1024 chunks of 16B
      int p = i * 256 + tid;
      int krow = p >> 5, pj = p & 31;
      int j = (pj & ~7) | ((pj ^ krow) & 7);       // involution source swizzle
      async_copy16(kbase + (size_t)(kvb + krow) * 256 + j * 8,
                   Kls + bb * 8192 + p * 16 / 2);
    }
#pragma unroll
    for (int i = 0; i < 5; ++i) {                  // V: 1280 chunks (5/row)
      int p = i * 256 + tid;
      int vrow = p / 5, slot = p % 5;
      int col = (slot & 3) * 8;                    // slot 4 = dup pad load
      async_copy16(vtb + (size_t)vrow * SEQ + kvb + col,
                   Vls + bb * 10240 + p * 8);
    }
  };

  int cur = 0;
  stage(0, t0);
  __syncthreads();                                 // drains vmcnt(0)

  for (int t = t0; t <= t1; ++t) {
    const int kvb = t * 32;
    if (t + 1 <= t1) stage(cur ^ 1, t + 1);        // async prefetch next tile

    if (kvb <= qb + 31) {                          // skip fully-masked waves
      const unsigned short* Kc = Kls + cur * 8192;
      const unsigned short* Vc = Vls + cur * 10240;

      // ---- S^T[kv,q] = K.Q^T : A = K rows (kv), B = Q rows (q), 2 q-groups
      f32x4 s[2][2] = {};
      __builtin_amdgcn_s_setprio(1);
#pragma unroll
      for (int n = 0; n < 2; ++n) {
        const int row = n * 16 + l15;
#pragma unroll
        for (int kc = 0; kc < 8; ++kc) {
          int j  = kc * 4 + lg;
          int pj = (j & ~7) | ((j ^ row) & 7);
          bf16x8 kf = *reinterpret_cast<const bf16x8*>(Kc + (row * 32 + pj) * 8);
          s[0][n] = __builtin_amdgcn_mfma_f32_16x16x32_bf16(kf, qf[0][kc], s[0][n], 0, 0, 0);
          s[1][n] = __builtin_amdgcn_mfma_f32_16x16x32_bf16(kf, qf[1][kc], s[1][n], 0, 0, 0);
        }
      }
      __builtin_amdgcn_s_setprio(0);

      // causal mask: element (kv,q) masked if kv > q
      if (kvb + 31 > qb) {
#pragma unroll
        for (int g = 0; g < 2; ++g)
#pragma unroll
          for (int n = 0; n < 2; ++n)
#pragma unroll
            for (int r = 0; r < 4; ++r)
              if (kvb + n * 16 + lg * 4 + r > qb + 16 * g + l15)
                s[g][n][r] = -1e30f;
      }

      // ---- online softmax, per group; row q = l15 shared by 4 lanes (lg)
      float pm0 = fmaxf(fmaxf(fmaxf(s[0][0][0], s[0][0][1]), fmaxf(s[0][0][2], s[0][0][3])),
                        fmaxf(fmaxf(s[0][1][0], s[0][1][1]), fmaxf(s[0][1][2], s[0][1][3])));
      float pm1 = fmaxf(fmaxf(fmaxf(s[1][0][0], s[1][0][1]), fmaxf(s[1][0][2], s[1][0][3])),
                        fmaxf(fmaxf(s[1][1][0], s[1][1][1]), fmaxf(s[1][1][2], s[1][1][3])));
      pm0 = fmaxf(pm0, __shfl_xor(pm0, 16));
      pm0 = fmaxf(pm0, __shfl_xor(pm0, 32));
      pm1 = fmaxf(pm1, __shfl_xor(pm1, 16));
      pm1 = fmaxf(pm1, __shfl_xor(pm1, 32));

      if (__any((pm0 > m0r + 8.0f) || (pm1 > m1r + 8.0f))) {   // defer-max
        float mn0 = fmaxf(m0r, pm0), mn1 = fmaxf(m1r, pm1);
        float sc0 = __expf(m0r - mn0), sc1 = __expf(m1r - mn1);
#pragma unroll
        for (int i = 0; i < 16; ++i)
#pragma unroll
          for (int r = 0; r < 4; ++r) {
            o[i][0][r] *= sc0;
            o[i][1][r] *= sc1;
          }
        l0r *= sc0; l1r *= sc1;
        m0r = mn0;  m1r = mn1;
      }

#pragma unroll
      for (int n = 0; n < 2; ++n)
#pragma unroll
        for (int r = 0; r < 4; ++r) {
          s[0][n][r] = __expf(s[0][n][r] - m0r);
          s[1][n][r] = __expf(s[1][n][r] - m1r);
        }

      float rs0 = ((s[0][0][0] + s[0][0][1]) + (s[0][0][2] + s[0][0][3])) +
                  ((s[0][1][0] + s[0][1][1]) + (s[0][1][2] + s[0][1][3]));
      float rs1 = ((s[1][0][0] + s[1][0][1]) + (s[1][0][2] + s[1][0][3])) +
                  ((s[1][1][0] + s[1][1][1]) + (s[1][1][2] + s[1][1][3]));
      rs0 += __shfl_xor(rs0, 16); rs0 += __shfl_xor(rs0, 32);
      rs1 += __shfl_xor(rs1, 16); rs1 += __shfl_xor(rs1, 32);
      l0r += rs0; l1r += rs1;

      // ---- P redistribution, in-register (cvt_pk + ds_bpermute):
      // lane (l15,lg) owns P[q=l15][kv=16n+4lg+r]; B-frag needs kv=8lg..8lg+7.
      // src lane for dwords 0,1 = l15+32*(lg&1); dwords 2,3 = +16 more.
      // src reg pair index n_src = lg>>1.
      bf16x8 pb[2];
      {
        const int alo = (l15 + ((lg & 1) << 5)) << 2;   // byte addr = lane*4
        const int ahi = alo + 64;
        const bool lo2 = (lg < 2);
#pragma unroll
        for (int g = 0; g < 2; ++g) {
          unsigned int w00 = cvtpk(s[g][0][0], s[g][0][1]);
          unsigned int w01 = cvtpk(s[g][0][2], s[g][0][3]);
          unsigned int w10 = cvtpk(s[g][1][0], s[g][1][1]);
          unsigned int w11 = cvtpk(s[g][1][2], s[g][1][3]);
          u32x4 pd;
          unsigned int a0 = __builtin_amdgcn_ds_bpermute(alo, w00);
          unsigned int b0 = __builtin_amdgcn_ds_bpermute(alo, w10);
          pd.x = lo2 ? a0 : b0;
          unsigned int a1 = __builtin_amdgcn_ds_bpermute(alo, w01);
          unsigned int b1 = __builtin_amdgcn_ds_bpermute(alo, w11);
          pd.y = lo2 ? a1 : b1;
          unsigned int a2 = __builtin_amdgcn_ds_bpermute(ahi, w00);
          unsigned int b2 = __builtin_amdgcn_ds_bpermute(ahi, w10);
          pd.z = lo2 ? a2 : b2;
          unsigned int a3 = __builtin_amdgcn_ds_bpermute(ahi, w01);
          unsigned int b3 = __builtin_amdgcn_ds_bpermute(ahi, w11);
          pd.w = lo2 ? a3 : b3;
          pb[g] = __builtin_bit_cast(bf16x8, pd);
        }
      }

      // ---- O^T[d,q] += V^T.P^T : A = V^T rows (d, pad-40), B = P rows (q)
      __builtin_amdgcn_s_setprio(1);
#pragma unroll
      for (int dt = 0; dt < 16; ++dt) {
        bf16x8 vf = *reinterpret_cast<const bf16x8*>(
            Vc + (dt * 16 + l15) * 40 + lg * 8);
        o[dt][0] = __builtin_amdgcn_mfma_f32_16x16x32_bf16(vf, pb[0], o[dt][0], 0, 0, 0);
        o[dt][1] = __builtin_amdgcn_mfma_f32_16x16x32_bf16(vf, pb[1], o[dt][1], 0, 0, 0);
      }
      __builtin_amdgcn_s_setprio(0);
    }

    __syncthreads();                               // drain prefetch + LDS reuse
    cur ^= 1;
  }

  // ---- epilogue: lane holds O^T[d = dt*16+lg*4+r, q = qb+16g+l15], UNNORM.
#pragma unroll
  for (int g = 0; g < 2; ++g) {
    const int qrow = qb + 16 * g + l15;
    const int rid = h * SEQ + qrow;
    const float mg = g ? m1r : m0r;
    const float lg_ = g ? l1r : l0r;
    if (c == 0) {
#pragma unroll
      for (int dt = 0; dt < 16; ++dt) {
        ushort4 w;
        w.x = f2bf(o[dt][g][0]); w.y = f2bf(o[dt][g][1]);
        w.z = f2bf(o[dt][g][2]); w.w = f2bf(o[dt][g][3]);
        *reinterpret_cast<ushort4*>(
            attn + (size_t)qrow * HID + h * 256 + dt * 16 + lg * 4) = w;
      }
      if (lg == 0) reinterpret_cast<float2*>(ml)[rid] = float2{mg, lg_};
    } else {
#pragma unroll
      for (int dt = 0; dt < 16; ++dt) {
        ushort4 w;
        w.x = f2bf(o[dt][g][0]); w.y = f2bf(o[dt][g][1]);
        w.z = f2bf(o[dt][g][2]); w.w = f2bf(o[dt][g][3]);
        *reinterpret_cast<ushort4*>(opart + (size_t)rid * 256 + dt * 16 + lg * 4) = w;
      }
      if (lg == 0) reinterpret_cast<float2*>(ml)[32768 + rid] = float2{mg, lg_};
    }
  }
}

// ----------------------------------------------------- split-KV merge pass
// every q-row has exactly 2 partials: c0 (in attn, unnormalized) + c1 (opart).
__global__ __launch_bounds__(256) void merge(const unsigned short* __restrict__ opart,
                                             const float* __restrict__ ml,
                                             unsigned short* __restrict__ attn) {
  const int wid = threadIdx.x >> 6, lane = threadIdx.x & 63;
  const int rid = blockIdx.x * 4 + wid;           // 0..32767 = h*4096 + s
  const int h = rid >> 12, s = rid & 4095;

  float2 ab0 = reinterpret_cast<const float2*>(ml)[rid];
  float2 ab1 = reinterpret_cast<const float2*>(ml)[32768 + rid];
  float M  = fmaxf(ab0.x, ab1.x);
  float w0 = __expf(ab0.x - M), w1 = __expf(ab1.x - M);
  float invL = 1.0f / (w0 * ab0.y + w1 * ab1.y);
  w0 *= invL; w1 *= invL;

  unsigned short* arow = attn + (size_t)s * HID + h * 256;
  ushort4 a = reinterpret_cast<const ushort4*>(arow)[lane];
  ushort4 bq = reinterpret_cast<const ushort4*>(opart + (size_t)rid * 256)[lane];
  ushort4 o;
  o.x = f2bf(w0 * bf2f(a.x) + w1 * bf2f(bq.x));
  o.y = f2bf(w0 * bf2f(a.y) + w1 * bf2f(bq.y));
  o.z = f2bf(w0 * bf2f(a.z) + w1 * bf2f(bq.z));
  o.w = f2bf(w0 * bf2f(a.w) + w1 * bf2f(bq.w));
  reinterpret_cast<ushort4*>(arow)[lane] = o;
}

// ---------------------------------------------------------------- launcher
extern "C" void kernel_launch(void* const* d_in, const int* in_sizes, int n_in,
                              void* d_out, int out_size, void* d_ws, size_t ws_size,
                              hipStream_t stream) {
  const float* hs   = (const float*)d_in[0];
  const float* cosb = (const float*)d_in[1];
  const float* sinb = (const float*)d_in[2];
  const float* qkvw = (const float*)d_in[3];
  const float* ow   = (const float*)d_in[4];

  char* ws = (char*)d_ws;
  unsigned short* hs_bf   = (unsigned short*)(ws + 0);           // 16 MB (dead after QKV GEMM)
  unsigned short* wqkv_bf = (unsigned short*)(ws + 16777216);    // 12 MB (dead after QKV GEMM)
  unsigned short* wo_bf   = (unsigned short*)(ws + 29360128);    //  8 MB (live till final GEMM)
  unsigned short* qkv_bf  = (unsigned short*)(ws + 37748736);    // 24 MB (dead after postproc)
  unsigned short* attn_bf = qkv_bf;                              // 16 MB overlay
  unsigned short* q_bf    = (unsigned short*)(ws + 62914560);    // 16 MB
  unsigned short* k_bf    = (unsigned short*)(ws + 79691776);    //  4 MB
  unsigned short* vt_bf   = (unsigned short*)(ws + 83886080);    //  4 MB
  // flash partial overlays (regions dead after the QKV GEMM):
  unsigned short* opart   = (unsigned short*)(ws + 0);           // 16 MB (c1 partials)
  float*          mlbuf   = (float*)(ws + 26214400);             // 512 KB (2x32768 float2)

  cvt_bf16<<<dim3((SEQ * HID / 4 + 255) / 256), dim3(256), 0, stream>>>(hs, hs_bf, SEQ * HID / 4);
  cvt_bf16<<<dim3((QKVN * HID / 4 + 255) / 256), dim3(256), 0, stream>>>(qkvw, wqkv_bf, QKVN * HID / 4);
  cvt_bf16<<<dim3((HID * HID / 4 + 255) / 256), dim3(256), 0, stream>>>(ow, wo_bf, HID * HID / 4);

  gemm_bt<true><<<dim3(QKVN / 128, SEQ / 128), dim3(256), 0, stream>>>(
      hs_bf, wqkv_bf, qkv_bf, SEQ, QKVN, HID);

  postproc<<<dim3(SEQ * 12 / 4), dim3(256), 0, stream>>>(qkv_bf, cosb, sinb, q_bf, k_bf, vt_bf);

  flash<<<dim3(512), dim3(256), 73728, stream>>>(q_bf, k_bf, vt_bf, attn_bf, opart, mlbuf);

  merge<<<dim3(8192), dim3(256), 0, stream>>>(opart, mlbuf, attn_bf);

  gemm_bt<false><<<dim3(HID / 128, SEQ / 128), dim3(256), 0, stream>>>(
      attn_bf, wo_bf, d_out, SEQ, HID, HID);
}